// Round 15
// baseline (186.607 us; speedup 1.0000x reference)
//
#include <hip/hip_runtime.h>

#define I_DIM 17
#define H_DIM 128
#define T_DIM 19
#define B_DIM 32768
#define M_ROWS 64
#define NTHR 1024
#define GRID (B_DIM / M_ROWS) /* 512 blocks, 1/CU, 2 passes */
#define XI 323
#define XSLOT 2176            /* per-t x slot: 4 rowgrp x 512B (k0..15) + 128B k16 plane */

/* LDS map */
#define OFF_WHH 0             /* 128 frags x 1024 = 131072 */
#define OFF_H   131072        /* H0 @ +0 (8K, rows 0..31), H1 @ +8192 (rows 32..63) */
#define OFF_X   147456        /* 2 slots x 2176 = 4352 */
#define LDS_TOT 151808

typedef __bf16 bf16x8 __attribute__((ext_vector_type(8)));
typedef float f32x4 __attribute__((ext_vector_type(4)));
typedef float f32x4u __attribute__((ext_vector_type(4), aligned(4)));
union FragU { bf16x8 v; unsigned short s[8]; uint4 u; };

#define K1 1.4426950408889634f
#define K2 2.8853900817779268f

__device__ __forceinline__ unsigned short f2bf(float f) {
    union { float f; unsigned u; } x; x.f = f;
    return (unsigned short)((x.u + 0x8000u) >> 16);
}

/* gates MFMA (transposed D) for this wave's group: 2 row-tiles x 4 gates.
   XP_: x slot (compile-time). Bias enters via k17 of wihr. */
#define MFMA_G(XP_, REC_, DOY_) do {                                              \
    _Pragma("unroll") for (int m = 0; m < 2; ++m) {                               \
        FragU fx; fx.u = (uint4){0u, 0u, 0u, 0u};                                 \
        if (q < 2)                                                                \
            fx.v = *(const bf16x8*)(smem + vxy + ((XP_) * XSLOT + m * 512));      \
        else if (q == 2) {                                                        \
            fx.s[0] = *(const unsigned short*)(smem + vx16 + ((XP_) * XSLOT + m * 32)); \
            fx.s[1] = (unsigned short)0x3F80;                                     \
        }                                                                         \
        _Pragma("unroll") for (int g = 0; g < 4; ++g) {                           \
            f32x4 z = {0.f, 0.f, 0.f, 0.f};                                       \
            acc[m][g] = __builtin_amdgcn_mfma_f32_16x16x32_bf16(wihr[g], fx.v, z, 0, 0, 0); \
        }                                                                         \
    }                                                                             \
    if (REC_) {                                                                   \
        _Pragma("unroll") for (int kk = 0; kk < 4; ++kk) {                        \
            bf16x8 aw[4];                                                         \
            _Pragma("unroll") for (int g = 0; g < 4; ++g)                         \
                aw[g] = *(const bf16x8*)(smem + vwhh + (kk * 4096 + g * 1024));   \
            _Pragma("unroll") for (int m = 0; m < 2; ++m) {                       \
                bf16x8 hb = *(const bf16x8*)(smem + vkk[kk] + m * 4096);          \
                _Pragma("unroll") for (int g = 0; g < 4; ++g)                     \
                    acc[m][g] = __builtin_amdgcn_mfma_f32_16x16x32_bf16(aw[g], hb, acc[m][g], 0, 0, 0); \
            }                                                                     \
        }                                                                         \
    }                                                                             \
    if (DOY_) Y_ONLY();                                                           \
} while (0)

/* y^T for this group's previous h (waves with cg<4) */
#define Y_ONLY() do {                                                             \
    if (yw) {                                                                     \
        f32x4 ya = {0.f, 0.f, 0.f, 0.f};                                          \
        _Pragma("unroll") for (int kk = 0; kk < 4; ++kk) {                        \
            bf16x8 hb = *(const bf16x8*)(smem + vyv[kk]);                         \
            ya = __builtin_amdgcn_mfma_f32_16x16x32_bf16(wor[kk], hb, ya, 0, 0, 0); \
        }                                                                         \
        if (yct == 0) { *(f32x4u*)ypt = ya + ybo; }                               \
        else if (q == 0) { ypt[0] = ya[0] + ybo[0]; }                             \
        ypt += I_DIM;                                                             \
    }                                                                             \
} while (0)

/* elementwise for both tiles + packed b64 h-writes */
#define ELEM_G() do {                                                             \
    _Pragma("unroll") for (int m = 0; m < 2; ++m) {                               \
        unsigned long long hp = 0ull;                                             \
        _Pragma("unroll") for (int r = 0; r < 4; ++r) {                           \
            float ui = __builtin_amdgcn_exp2f(acc[m][0][r]);                      \
            float uf = __builtin_amdgcn_exp2f(acc[m][1][r]);                      \
            float vg = __builtin_amdgcn_exp2f(acc[m][2][r]);                      \
            float uo = __builtin_amdgcn_exp2f(acc[m][3][r]);                      \
            float A_ = 1.f + ui, F_ = 1.f + uf, G_ = 1.f + vg;                    \
            float AG = A_ * G_;                                                   \
            int ci = m * 4 + r;                                                   \
            float c = (cst[ci] * AG + (1.f - vg) * F_) * __builtin_amdgcn_rcpf(F_ * AG); \
            cst[ci] = c;                                                          \
            float vc = __builtin_amdgcn_exp2f(-K2 * c);                           \
            float h = (1.f - vc) * __builtin_amdgcn_rcpf((1.f + uo) * (1.f + vc));\
            union { float f; unsigned u; } hu; hu.f = h;                          \
            hp |= (unsigned long long)((hu.u + 0x8000u) >> 16) << (16 * r);       \
        }                                                                         \
        *(unsigned long long*)(smem + vwrT + m * 4096) = hp;                      \
    }                                                                             \
} while (0)

/* x staging (G1 threads only): 3 elems/thread covers 1088 */
#define STAGE(XP_) do {                                                           \
    float v1 = xs1[0];                                                            \
    float v2 = xs2[0];                                                            \
    float v3 = sv3 ? xs3[0] : 0.f;                                                \
    xs1 += I_DIM; xs2 += I_DIM; xs3 += I_DIM;                                     \
    *(unsigned short*)(smem + xd1 + (XP_) * XSLOT) = f2bf(v1);                    \
    *(unsigned short*)(smem + xd2 + (XP_) * XSLOT) = f2bf(v2);                    \
    if (sv3) *(unsigned short*)(smem + xd3 + (XP_) * XSLOT) = f2bf(v3);           \
} while (0)

__global__ __launch_bounds__(NTHR)
__attribute__((amdgpu_waves_per_eu(4, 4)))
void flowlstm(
    const float* __restrict__ x, const float* __restrict__ W_ih,
    const float* __restrict__ W_hh, const float* __restrict__ b_ih,
    const float* __restrict__ b_hh, const float* __restrict__ W_out,
    const float* __restrict__ b_out, float* __restrict__ out)
{
    __shared__ __align__(16) unsigned char smem[LDS_TOT];
    const int tid = threadIdx.x;
    const int w = tid >> 6, lane = tid & 63, l15 = lane & 15, q = lane >> 4;
    const int grp = w >> 3;                 /* 0: rows 0..31, 1: rows 32..63 */
    const bool isG1 = (grp == 1);
    const int cg = w & 7;                   /* gate-col group */
    const int b0 = blockIdx.x * M_ROWS;

    /* ---- stage W_hh -> LDS frags, PRE-SCALED (128 frags = cg*16+kk*4+g) ---- */
    #pragma unroll
    for (int i = 0; i < 8; ++i) {
        int s = tid + i * NTHR;
        int ln = s & 63, f = s >> 6;
        int g = f & 3, kk = (f >> 2) & 3, cgs = f >> 4;
        float sc = (g == 2) ? -K2 : -K1;
        int n = g * H_DIM + cgs * 16 + (ln & 15);
        const float* sp = W_hh + n * H_DIM + kk * 32 + (ln >> 4) * 8;
        FragU fu;
        #pragma unroll
        for (int e = 0; e < 8; ++e) fu.s[e] = f2bf(sp[e] * sc);
        *(uint4*)(smem + OFF_WHH + f * 1024 + ln * 16) = fu.u;
    }
    /* ---- W_ih fragments in regs, PRE-SCALED, bias at k=17 ---- */
    bf16x8 wihr[4];
    #pragma unroll
    for (int g = 0; g < 4; ++g) {
        float sc = (g == 2) ? -K2 : -K1;
        int n = g * H_DIM + cg * 16 + l15;
        FragU fu;
        #pragma unroll
        for (int e = 0; e < 8; ++e) {
            int k = q * 8 + e;
            float v = 0.f;
            if (k < I_DIM)       v = W_ih[n * I_DIM + k] * sc;
            else if (k == I_DIM) v = (b_ih[n] + b_hh[n]) * sc;
            fu.s[e] = f2bf(v);
        }
        wihr[g] = fu.v;
    }
    /* ---- W_out fragments in regs (waves cg<4 only use them) ---- */
    const bool yw = (cg < 4);
    const int yrt = (w >> 1) & 1, yct = w & 1;
    const int ycol = yct * 16 + 4 * q;      /* base col of this lane's 4 y regs */
    bf16x8 wor[4];
    #pragma unroll
    for (int kk = 0; kk < 4; ++kk) {
        int o = yct * 16 + l15;
        FragU fu;
        #pragma unroll
        for (int e = 0; e < 8; ++e)
            fu.s[e] = (o < I_DIM) ? f2bf(W_out[o * H_DIM + kk * 32 + q * 8 + e])
                                  : (unsigned short)0;
        wor[kk] = fu.v;
    }
    f32x4 ybo;
    #pragma unroll
    for (int r = 0; r < 4; ++r) {
        int col = ycol + r;
        ybo[r] = b_out[col < I_DIM ? col : 16];
    }
    /* ---- t-invariant LDS vaddrs ---- */
    const unsigned xr7 = (unsigned)((l15 & 7) << 4);
    const unsigned hbase = (unsigned)(OFF_H + grp * 8192);
    unsigned vkk[4], vyv[4];
    #pragma unroll
    for (int kk = 0; kk < 4; ++kk) {
        unsigned sw = (unsigned)((kk * 64 + q * 16) ^ xr7);
        vkk[kk] = hbase + (unsigned)(l15 * 256) + sw;
        vyv[kk] = hbase + (unsigned)(yrt * 4096 + l15 * 256) + sw;
    }
    const unsigned vwrT = hbase + (unsigned)(l15 * 256 + (((cg * 16 + 4 * q) * 2) ^ xr7));
    const unsigned vwhh = (unsigned)(OFF_WHH + cg * 16384 + lane * 16);
    const unsigned vxy  = (unsigned)(OFF_X + grp * 1024 + (q < 2 ? q * 256 : 0) + l15 * 16);
    const unsigned vx16 = (unsigned)(OFF_X + 2048 + grp * 64 + l15 * 2);
    float* ypt = out + (size_t)(b0 + grp * 32 + yrt * 16 + l15) * XI + (yct ? 16 : 4 * q);

    /* ---- x staging map (G1 threads; g_tid in 0..511, 3 elems cover 1088) ---- */
    const int g_tid = tid & 511;
    const unsigned e1 = (unsigned)g_tid, e2 = e1 + 512u, e3 = e1 + 1024u;
    const bool sv3 = (g_tid < 64);
    const unsigned r1 = (e1 * 61681u) >> 20, k1v = e1 - r1 * 17u;
    const unsigned r2 = (e2 * 61681u) >> 20, k2v = e2 - r2 * 17u;
    const unsigned r3 = (e3 * 61681u) >> 20, k3v = e3 - r3 * 17u;
    const unsigned xd1 = (k1v == 16u) ? (unsigned)(OFF_X + 2048 + r1 * 2)
        : (unsigned)(OFF_X + (r1 >> 4) * 512 + (k1v >> 3) * 256 + (r1 & 15) * 16 + (k1v & 7) * 2);
    const unsigned xd2 = (k2v == 16u) ? (unsigned)(OFF_X + 2048 + r2 * 2)
        : (unsigned)(OFF_X + (r2 >> 4) * 512 + (k2v >> 3) * 256 + (r2 & 15) * 16 + (k2v & 7) * 2);
    const unsigned xd3 = (k3v == 16u) ? (unsigned)(OFF_X + 2048 + r3 * 2)
        : (unsigned)(OFF_X + (r3 >> 4) * 512 + (k3v >> 3) * 256 + (r3 & 15) * 16 + (k3v & 7) * 2);
    const float* xs1 = x + (size_t)(b0 + r1) * XI + k1v;
    const float* xs2 = x + (size_t)(b0 + r2) * XI + k2v;
    const float* xs3 = x + (size_t)(b0 + r3) * XI + k3v;

    float cst[8];
    #pragma unroll
    for (int i = 0; i < 8; ++i) cst[i] = 0.f;
    f32x4 acc[2][4];

    /* ---- prologue: G1 stages x_0 -> slot0 (whh staging above by all) ---- */
    if (isG1) STAGE(0);
    __syncthreads();

    /* r0: G0 MFMA(t0, slot0, noREC) | G1 stage x_1 -> slot1 */
    if (!isG1) MFMA_G(0, 0, 0);
    else       STAGE(1);
    __syncthreads();

    /* k=0 */
    if (!isG1) ELEM_G(); else MFMA_G(0, 0, 0);           /* rA: G1 MFMA(t0) */
    __syncthreads();
    if (!isG1) MFMA_G(1, 1, 1); else { ELEM_G(); STAGE(0); }  /* rB: G0 MFMA(t1)+Y(t0); G1 ELEM(t0)+stage t2 */
    __syncthreads();

    /* k = 1..16, pairs */
    #pragma unroll 1
    for (int p = 0; p < 8; ++p) {
        /* k odd: slot1 */
        if (!isG1) ELEM_G(); else MFMA_G(1, 1, 1);
        __syncthreads();
        if (!isG1) MFMA_G(0, 1, 1); else { ELEM_G(); STAGE(1); }
        __syncthreads();
        /* k even: slot0 */
        if (!isG1) ELEM_G(); else MFMA_G(0, 1, 1);
        __syncthreads();
        if (!isG1) MFMA_G(1, 1, 1); else { ELEM_G(); STAGE(0); }
        __syncthreads();
    }

    /* k=17 (slot1) */
    if (!isG1) ELEM_G(); else MFMA_G(1, 1, 1);
    __syncthreads();
    if (!isG1) MFMA_G(0, 1, 1); else ELEM_G();           /* G0 MFMA(t18)+Y(t17); no stage */
    __syncthreads();
    /* k=18 (slot0) */
    if (!isG1) ELEM_G(); else MFMA_G(0, 1, 1);           /* G1 MFMA(t18)+Y(t17) */
    __syncthreads();
    if (!isG1) { Y_ONLY(); } else ELEM_G();              /* G0 Y(t18); G1 ELEM(t18) */
    __syncthreads();
    if (isG1) Y_ONLY();                                  /* G1 Y(t18) */
}

extern "C" void kernel_launch(void* const* d_in, const int* in_sizes, int n_in,
                              void* d_out, int out_size, void* d_ws, size_t ws_size,
                              hipStream_t stream) {
    const float* x     = (const float*)d_in[0];
    const float* W_ih  = (const float*)d_in[1];
    const float* W_hh  = (const float*)d_in[2];
    const float* b_ih  = (const float*)d_in[3];
    const float* b_hh  = (const float*)d_in[4];
    const float* W_out = (const float*)d_in[5];
    const float* b_out = (const float*)d_in[6];
    float* out = (float*)d_out;

    dim3 grid(GRID), block(NTHR);
    flowlstm<<<grid, block, 0, stream>>>(x, W_ih, W_hh, b_ih, b_hh, W_out, b_out, out);
}

// Round 16
// 163.626 us; speedup vs baseline: 1.1404x; 1.1404x over previous
//
#include <hip/hip_runtime.h>

#define I_DIM 17
#define H_DIM 128
#define T_DIM 19
#define B_DIM 32768
#define M_ROWS 64
#define NTHR 1024
#define GRID (B_DIM / M_ROWS) /* 512 blocks, 1/CU, 2 passes */
#define XI 323
#define XSLOT 2176            /* per-t x slot: 4 rowgrp x 512B (k0..15) + 128B k16 plane */

/* LDS map */
#define OFF_WHH 0             /* W_hh kk=2,3: 64 frags x 1024 = 65536 */
#define OFF_WI  65536         /* W_ih: 32 frags = 32768 (bias folded at k17) */
#define OFF_WO  98304         /* W_out: 8 frags = 8192 */
#define OFF_H   106496        /* H0 (rows 0..31) 8K, H1 (rows 32..63) 8K */
#define OFF_X   122880        /* 2 slots x 2176 */
#define LDS_TOT 127232

typedef __bf16 bf16x8 __attribute__((ext_vector_type(8)));
typedef float f32x4 __attribute__((ext_vector_type(4)));
typedef float f32x4u __attribute__((ext_vector_type(4), aligned(4)));
union FragU { bf16x8 v; unsigned short s[8]; uint4 u; };

#define K1 1.4426950408889634f
#define K2 2.8853900817779268f

__device__ __forceinline__ unsigned short f2bf(float f) {
    union { float f; unsigned u; } x; x.f = f;
    return (unsigned short)((x.u + 0x8000u) >> 16);
}

/* gates MFMA (transposed D) for this wave's group: 2 row-tiles x 4 gates.
   wihr from LDS; whh kk0,1 from regs, kk2,3 from LDS. Bias via k17. */
#define MFMA_G(XP_, REC_) do {                                                    \
    bf16x8 wi_[4];                                                                \
    _Pragma("unroll") for (int g = 0; g < 4; ++g)                                 \
        wi_[g] = *(const bf16x8*)(smem + vwi + g * 1024);                         \
    _Pragma("unroll") for (int m = 0; m < 2; ++m) {                               \
        FragU fx; fx.u = (uint4){0u, 0u, 0u, 0u};                                 \
        if (q < 2)                                                                \
            fx.v = *(const bf16x8*)(smem + vxy + ((XP_) * XSLOT + m * 512));      \
        else if (q == 2) {                                                        \
            fx.s[0] = *(const unsigned short*)(smem + vx16 + ((XP_) * XSLOT + m * 32)); \
            fx.s[1] = (unsigned short)0x3F80;                                     \
        }                                                                         \
        _Pragma("unroll") for (int g = 0; g < 4; ++g) {                           \
            f32x4 z = {0.f, 0.f, 0.f, 0.f};                                       \
            acc[m][g] = __builtin_amdgcn_mfma_f32_16x16x32_bf16(wi_[g], fx.v, z, 0, 0, 0); \
        }                                                                         \
    }                                                                             \
    if (REC_) {                                                                   \
        _Pragma("unroll") for (int kk = 0; kk < 2; ++kk)                          \
            _Pragma("unroll") for (int m = 0; m < 2; ++m) {                       \
                bf16x8 hb = *(const bf16x8*)(smem + vkk[kk] + m * 4096);          \
                _Pragma("unroll") for (int g = 0; g < 4; ++g)                     \
                    acc[m][g] = __builtin_amdgcn_mfma_f32_16x16x32_bf16(whh[kk][g], hb, acc[m][g], 0, 0, 0); \
            }                                                                     \
        _Pragma("unroll") for (int kr = 0; kr < 2; ++kr) {                        \
            bf16x8 aw[4];                                                         \
            _Pragma("unroll") for (int g = 0; g < 4; ++g)                         \
                aw[g] = *(const bf16x8*)(smem + vwhh + (kr * 4096 + g * 1024));   \
            _Pragma("unroll") for (int m = 0; m < 2; ++m) {                       \
                bf16x8 hb = *(const bf16x8*)(smem + vkk[2 + kr] + m * 4096);      \
                _Pragma("unroll") for (int g = 0; g < 4; ++g)                     \
                    acc[m][g] = __builtin_amdgcn_mfma_f32_16x16x32_bf16(aw[g], hb, acc[m][g], 0, 0, 0); \
            }                                                                     \
        }                                                                         \
    }                                                                             \
} while (0)

/* elementwise + packed b64 h-writes (consumes acc) */
#define ELEM_G() do {                                                             \
    _Pragma("unroll") for (int m = 0; m < 2; ++m) {                               \
        unsigned long long hp = 0ull;                                             \
        _Pragma("unroll") for (int r = 0; r < 4; ++r) {                           \
            float ui = __builtin_amdgcn_exp2f(acc[m][0][r]);                      \
            float uf = __builtin_amdgcn_exp2f(acc[m][1][r]);                      \
            float vg = __builtin_amdgcn_exp2f(acc[m][2][r]);                      \
            float uo = __builtin_amdgcn_exp2f(acc[m][3][r]);                      \
            float A_ = 1.f + ui, F_ = 1.f + uf, G_ = 1.f + vg;                    \
            float AG = A_ * G_;                                                   \
            int ci = m * 4 + r;                                                   \
            float c = (cst[ci] * AG + (1.f - vg) * F_) * __builtin_amdgcn_rcpf(F_ * AG); \
            cst[ci] = c;                                                          \
            float vc = __builtin_amdgcn_exp2f(-K2 * c);                           \
            float h = (1.f - vc) * __builtin_amdgcn_rcpf((1.f + uo) * (1.f + vc));\
            union { float f; unsigned u; } hu; hu.f = h;                          \
            hp |= (unsigned long long)((hu.u + 0x8000u) >> 16) << (16 * r);       \
        }                                                                         \
        *(unsigned long long*)(smem + vwrT + m * 4096) = hp;                      \
    }                                                                             \
} while (0)

/* y^T for previous h (G0 waves only; wor from LDS) */
#define Y_ONLY() do {                                                             \
    f32x4 ya = {0.f, 0.f, 0.f, 0.f};                                              \
    _Pragma("unroll") for (int kk = 0; kk < 4; ++kk) {                            \
        bf16x8 wa = *(const bf16x8*)(smem + vwo + kk * 1024);                     \
        bf16x8 hb = *(const bf16x8*)(smem + vyh[kk]);                             \
        ya = __builtin_amdgcn_mfma_f32_16x16x32_bf16(wa, hb, ya, 0, 0, 0);        \
    }                                                                             \
    if (yct == 0) { *(f32x4u*)ypt = ya + ybo; }                                   \
    else if (q == 0) { ypt[0] = ya[0] + ybo[0]; }                                 \
    ypt += I_DIM;                                                                 \
} while (0)

__global__ __launch_bounds__(NTHR)
__attribute__((amdgpu_waves_per_eu(4, 4)))
void flowlstm(
    const float* __restrict__ x, const float* __restrict__ W_ih,
    const float* __restrict__ W_hh, const float* __restrict__ b_ih,
    const float* __restrict__ b_hh, const float* __restrict__ W_out,
    const float* __restrict__ b_out, float* __restrict__ out)
{
    __shared__ __align__(16) unsigned char smem[LDS_TOT];
    const int tid = threadIdx.x;
    const int w = tid >> 6, lane = tid & 63, l15 = lane & 15, q = lane >> 4;
    const int grp = w >> 3;                 /* 0: rows 0..31 (+y); 1: rows 32..63 (+staging) */
    const bool isG1 = (grp == 1);
    const int cg = w & 7;
    const int b0 = blockIdx.x * M_ROWS;

    /* ---- stage W_hh kk=2,3 -> LDS, PRE-SCALED (64 frags: cg*8+kr*4+g) ---- */
    #pragma unroll
    for (int i = 0; i < 4; ++i) {
        int s = tid + i * NTHR;
        int ln = s & 63, f = s >> 6;
        int g = f & 3, kr = (f >> 2) & 1, cgs = f >> 3;
        float sc = (g == 2) ? -K2 : -K1;
        int n = g * H_DIM + cgs * 16 + (ln & 15);
        const float* sp = W_hh + n * H_DIM + (2 + kr) * 32 + (ln >> 4) * 8;
        FragU fu;
        #pragma unroll
        for (int e = 0; e < 8; ++e) fu.s[e] = f2bf(sp[e] * sc);
        *(uint4*)(smem + OFF_WHH + f * 1024 + ln * 16) = fu.u;
    }
    /* ---- stage W_ih -> LDS (32 frags: cg*4+g), PRE-SCALED, bias at k17 ---- */
    #pragma unroll
    for (int i = 0; i < 2; ++i) {
        int s = tid + i * NTHR;
        int ln = s & 63, f = s >> 6;
        int g = f & 3, cgs = f >> 2;
        float sc = (g == 2) ? -K2 : -K1;
        int n = g * H_DIM + cgs * 16 + (ln & 15);
        FragU fu;
        #pragma unroll
        for (int e = 0; e < 8; ++e) {
            int k = (ln >> 4) * 8 + e;
            float v = 0.f;
            if (k < I_DIM)       v = W_ih[n * I_DIM + k] * sc;
            else if (k == I_DIM) v = (b_ih[n] + b_hh[n]) * sc;
            fu.s[e] = f2bf(v);
        }
        *(uint4*)(smem + OFF_WI + f * 1024 + ln * 16) = fu.u;
    }
    /* ---- stage W_out -> LDS (8 frags: ct*4+kk) ---- */
    if (tid < 512) {
        int ln = tid & 63, f = tid >> 6;
        int kk = f & 3, ct = f >> 2;
        int o = ct * 16 + (ln & 15);
        int kb = kk * 32 + (ln >> 4) * 8;
        FragU fu;
        #pragma unroll
        for (int e = 0; e < 8; ++e)
            fu.s[e] = (o < I_DIM) ? f2bf(W_out[o * H_DIM + kb + e]) : (unsigned short)0;
        *(uint4*)(smem + OFF_WO + f * 1024 + ln * 16) = fu.u;
    }
    /* ---- W_hh kk=0,1 in regs, PRE-SCALED (8 frags = 32 regs) ---- */
    bf16x8 whh[2][4];
    #pragma unroll
    for (int kk = 0; kk < 2; ++kk)
        #pragma unroll
        for (int g = 0; g < 4; ++g) {
            float sc = (g == 2) ? -K2 : -K1;
            int n = g * H_DIM + cg * 16 + l15;
            const float* sp = W_hh + n * H_DIM + kk * 32 + q * 8;
            FragU fu;
            #pragma unroll
            for (int e = 0; e < 8; ++e) fu.s[e] = f2bf(sp[e] * sc);
            whh[kk][g] = fu.v;
        }
    /* ---- t-invariant LDS vaddrs ---- */
    const unsigned xr7 = (unsigned)((l15 & 7) << 4);
    const unsigned hbase = (unsigned)(OFF_H + grp * 8192);
    unsigned vkk[4];
    #pragma unroll
    for (int kk = 0; kk < 4; ++kk)
        vkk[kk] = hbase + (unsigned)(l15 * 256) + (unsigned)(((kk * 64 + q * 16)) ^ xr7);
    const unsigned vwrT = hbase + (unsigned)(l15 * 256 + (((cg * 16 + 4 * q) * 2) ^ xr7));
    const unsigned vwhh = (unsigned)(OFF_WHH + cg * 8192 + lane * 16);
    const unsigned vwi  = (unsigned)(OFF_WI + cg * 4096 + lane * 16);
    const unsigned vxy  = (unsigned)(OFF_X + grp * 1024 + (q < 2 ? q * 256 : 0) + l15 * 16);
    const unsigned vx16 = (unsigned)(OFF_X + 2048 + grp * 64 + l15 * 2);

    /* ---- G0 role: y constants (yrt 0..3 spans H0+H1 contiguously) ---- */
    const int yrt = w >> 1, yct = w & 1;
    unsigned vyh[4];
    #pragma unroll
    for (int kk = 0; kk < 4; ++kk)
        vyh[kk] = (unsigned)(OFF_H + yrt * 4096 + l15 * 256) + (unsigned)(((kk * 64 + q * 16)) ^ xr7);
    const unsigned vwo = (unsigned)(OFF_WO + yct * 4096 + lane * 16);
    f32x4 ybo;
    #pragma unroll
    for (int r = 0; r < 4; ++r) {
        int col = yct * 16 + 4 * q + r;
        ybo[r] = b_out[col < I_DIM ? col : 16];
    }
    float* ypt = out + (size_t)(b0 + yrt * 16 + l15) * XI + (yct ? 16 : 4 * q);

    /* ---- G1 role: x staging map (512 threads, 3 elems cover 1088) ---- */
    const int g_tid = tid & 511;
    const unsigned e1 = (unsigned)g_tid, e2 = e1 + 512u, e3 = e1 + 1024u;
    const bool sv3 = (g_tid < 64);
    const unsigned r1 = (e1 * 61681u) >> 20, k1v = e1 - r1 * 17u;
    const unsigned r2 = (e2 * 61681u) >> 20, k2v = e2 - r2 * 17u;
    const unsigned r3 = (e3 * 61681u) >> 20, k3v = e3 - r3 * 17u;
    const unsigned xd1 = (k1v == 16u) ? (unsigned)(OFF_X + 2048 + r1 * 2)
        : (unsigned)(OFF_X + (r1 >> 4) * 512 + (k1v >> 3) * 256 + (r1 & 15) * 16 + (k1v & 7) * 2);
    const unsigned xd2 = (k2v == 16u) ? (unsigned)(OFF_X + 2048 + r2 * 2)
        : (unsigned)(OFF_X + (r2 >> 4) * 512 + (k2v >> 3) * 256 + (r2 & 15) * 16 + (k2v & 7) * 2);
    const unsigned xd3 = (k3v == 16u) ? (unsigned)(OFF_X + 2048 + r3 * 2)
        : (unsigned)(OFF_X + (r3 >> 4) * 512 + (k3v >> 3) * 256 + (r3 & 15) * 16 + (k3v & 7) * 2);
    const float* xs1 = x + (size_t)(b0 + r1) * XI + k1v;
    const float* xs2 = x + (size_t)(b0 + r2) * XI + k2v;
    const float* xs3 = x + (size_t)(b0 + r3) * XI + k3v;

    float cst[8];
    #pragma unroll
    for (int i = 0; i < 8; ++i) cst[i] = 0.f;
    f32x4 acc[2][4];

    /* ---- prologue: G1 stages x0 -> slot0, x1 -> slot1 ---- */
    if (isG1) {
        #pragma unroll
        for (int s = 0; s < 2; ++s) {
            float v1 = xs1[0], v2 = xs2[0], v3 = sv3 ? xs3[0] : 0.f;
            xs1 += I_DIM; xs2 += I_DIM; xs3 += I_DIM;
            *(unsigned short*)(smem + xd1 + s * XSLOT) = f2bf(v1);
            *(unsigned short*)(smem + xd2 + s * XSLOT) = f2bf(v2);
            if (sv3) *(unsigned short*)(smem + xd3 + s * XSLOT) = f2bf(v3);
        }
    }
    __syncthreads();

    /* r0: G0 MFMA(0, slot0, noREC) */
    if (!isG1) MFMA_G(0, 0);
    __syncthreads();
    /* r1: G0 ELEM(0) | G1 MFMA(0, slot0, noREC) */
    if (!isG1) ELEM_G(); else MFMA_G(0, 0);
    __syncthreads();

    /* ---- steps t (odd), t+1 (even) per iteration ---- */
    #pragma unroll 1
    for (int t = 1; t < T_DIM; t += 2) {
        /* rA: G0 MFMA(t,slot1)+Y_lo(t-1) | G1 load x(t+1); ELEM(t-1); write slot0 */
        if (!isG1) {
            MFMA_G(1, 1);
            if (w < 4) Y_ONLY();
        } else {
            float v1 = xs1[0], v2 = xs2[0], v3 = sv3 ? xs3[0] : 0.f;
            xs1 += I_DIM; xs2 += I_DIM; xs3 += I_DIM;
            ELEM_G();
            *(unsigned short*)(smem + xd1) = f2bf(v1);
            *(unsigned short*)(smem + xd2) = f2bf(v2);
            if (sv3) *(unsigned short*)(smem + xd3) = f2bf(v3);
        }
        __syncthreads();
        /* rB: G0 Y_hi(t-1)+ELEM(t) | G1 MFMA(t,slot1) */
        if (!isG1) {
            if (w >= 4) Y_ONLY();
            ELEM_G();
        } else {
            MFMA_G(1, 1);
        }
        __syncthreads();
        /* rA': G0 MFMA(t+1,slot0)+Y_lo(t) | G1 load x(t+2)?; ELEM(t); write slot1 */
        if (!isG1) {
            MFMA_G(0, 1);
            if (w < 4) Y_ONLY();
        } else {
            float v1 = 0.f, v2 = 0.f, v3 = 0.f;
            const bool st = (t + 2 < T_DIM);
            if (st) {
                v1 = xs1[0]; v2 = xs2[0]; if (sv3) v3 = xs3[0];
                xs1 += I_DIM; xs2 += I_DIM; xs3 += I_DIM;
            }
            ELEM_G();
            if (st) {
                *(unsigned short*)(smem + xd1 + XSLOT) = f2bf(v1);
                *(unsigned short*)(smem + xd2 + XSLOT) = f2bf(v2);
                if (sv3) *(unsigned short*)(smem + xd3 + XSLOT) = f2bf(v3);
            }
        }
        __syncthreads();
        /* rB': G0 Y_hi(t)+ELEM(t+1) | G1 MFMA(t+1,slot0) */
        if (!isG1) {
            if (w >= 4) Y_ONLY();
            ELEM_G();
        } else {
            MFMA_G(0, 1);
        }
        __syncthreads();
    }

    /* ---- tail: Y(18) + G1 ELEM(18) ---- */
    if (!isG1) {
        if (w < 4) Y_ONLY();           /* reads H0(18), written in last rB' */
    } else {
        ELEM_G();                      /* writes H1(18) */
    }
    __syncthreads();
    if (!isG1 && w >= 4) Y_ONLY();     /* reads H1(18) */
}

extern "C" void kernel_launch(void* const* d_in, const int* in_sizes, int n_in,
                              void* d_out, int out_size, void* d_ws, size_t ws_size,
                              hipStream_t stream) {
    const float* x     = (const float*)d_in[0];
    const float* W_ih  = (const float*)d_in[1];
    const float* W_hh  = (const float*)d_in[2];
    const float* b_ih  = (const float*)d_in[3];
    const float* b_hh  = (const float*)d_in[4];
    const float* W_out = (const float*)d_in[5];
    const float* b_out = (const float*)d_in[6];
    float* out = (float*)d_out;

    dim3 grid(GRID), block(NTHR);
    flowlstm<<<grid, block, 0, stream>>>(x, W_ih, W_hh, b_ih, b_hh, W_out, b_out, out);
}

// Round 17
// 153.814 us; speedup vs baseline: 1.2132x; 1.0638x over previous
//
#include <hip/hip_runtime.h>

#define I_DIM 17
#define H_DIM 128
#define T_DIM 19
#define B_DIM 32768
#define M_ROWS 128
#define NTHR 512
#define GRID (B_DIM / M_ROWS) /* 256 = one block per CU, ONE pass */
#define XI 323
#define NF (M_ROWS * XI)      /* 41344 */
#define XSLOT 4352            /* per-t x: 4 bt x 1024B frag + 256B k16 plane */

#define OFF_H 0               /* 2 x 32768 (128 rows x 256B, swizzled) */
#define OFF_X 65536           /* 19 x 4352 = 82688 */
#define LDS_TOT 148224

typedef __bf16 bf16x8 __attribute__((ext_vector_type(8)));
typedef float f32x4 __attribute__((ext_vector_type(4)));
typedef float f32x16 __attribute__((ext_vector_type(16)));
typedef float f32x4u __attribute__((ext_vector_type(4), aligned(4)));
union FragU { bf16x8 v; unsigned short s[8]; uint4 u; };

#define K1 1.4426950408889634f
#define K2 2.8853900817779268f

__device__ __forceinline__ unsigned short f2bf(float f) {
    union { float f; unsigned u; } x; x.f = f;
    return (unsigned short)((x.u + 0x8000u) >> 16);
}

/* read the 8 recurrent B-frags (h) for batch-tile BT_ from H[1-P] */
#define RB(BT_, P_) do {                                                          \
    _Pragma("unroll") for (int kk = 0; kk < 8; ++kk)                              \
        hb[kk] = *(const bf16x8*)(smem + OFF_H + (1 - (P_)) * 32768               \
                 + ((BT_) * 32 + l31) * 256 + ((kk * 32 + hi * 16) ^ sw15));      \
} while (0)

/* one 32x32 gate tile (rows = packed 8 hcol x 4 gate, cols = 32 batch).
   x-proj (2 MFMAs, bias folded at k17) + recurrent (8 MFMAs from hb). */
#define MQ(BT_, CTI_, ACC_, REC_) do {                                            \
    FragU f1; f1.v = *(const bf16x8*)(smem + xt + (BT_) * 1024 + lane * 16);      \
    FragU f2; f2.u = (uint4){0u, 0u, 0u, 0u};                                     \
    if (hi == 0) {                                                                \
        f2.s[0] = *(const unsigned short*)(smem + xt + 4096 + ((BT_) * 32 + l31) * 2); \
        f2.s[1] = (unsigned short)0x3F80;                                         \
    }                                                                             \
    f32x16 z = {0.f,0.f,0.f,0.f,0.f,0.f,0.f,0.f,0.f,0.f,0.f,0.f,0.f,0.f,0.f,0.f};\
    ACC_ = __builtin_amdgcn_mfma_f32_32x32x16_bf16(wihr[CTI_][0], f1.v, z, 0, 0, 0); \
    ACC_ = __builtin_amdgcn_mfma_f32_32x32x16_bf16(wihr[CTI_][1], f2.v, ACC_, 0, 0, 0); \
    if (REC_) {                                                                   \
        _Pragma("unroll") for (int kk = 0; kk < 8; ++kk)                          \
            ACC_ = __builtin_amdgcn_mfma_f32_32x32x16_bf16(whh[CTI_][kk], hb[kk], ACC_, 0, 0, 0); \
    }                                                                             \
} while (0)

/* elementwise for one tile: 4 quadruples/lane; b64 h-write into H[P] */
#define EQ(ACC_, TI_, CTI_, BT_, P_) do {                                         \
    unsigned long long hp = 0ull;                                                 \
    _Pragma("unroll") for (int jj = 0; jj < 4; ++jj) {                            \
        float ui = __builtin_amdgcn_exp2f(ACC_[jj]);                              \
        float uf = __builtin_amdgcn_exp2f(ACC_[4 + jj]);                          \
        float vg = __builtin_amdgcn_exp2f(ACC_[8 + jj]);                          \
        float uo = __builtin_amdgcn_exp2f(ACC_[12 + jj]);                         \
        float A_ = 1.f + ui, F_ = 1.f + uf, G_ = 1.f + vg;                        \
        float AG = A_ * G_;                                                       \
        int ci = (TI_) * 4 + jj;                                                  \
        float c = (cst[ci] * AG + (1.f - vg) * F_) * __builtin_amdgcn_rcpf(F_ * AG); \
        cst[ci] = c;                                                              \
        float vc = __builtin_amdgcn_exp2f(-K2 * c);                               \
        float h = (1.f - vc) * __builtin_amdgcn_rcpf((1.f + uo) * (1.f + vc));    \
        union { float f; unsigned u; } hu; hu.f = h;                              \
        hp |= (unsigned long long)((hu.u + 0x8000u) >> 16) << (16 * jj);          \
    }                                                                             \
    *(unsigned long long*)(smem + OFF_H + (P_) * 32768 + ((BT_) * 32 + l31) * 256 \
        + (((2 * w + (CTI_)) * 16 + hi * 8) ^ sw15)) = hp;                        \
} while (0)

/* y_{t-1} via 16x16 (verified R12 path); reads H[1-P] */
#define YB(P_) do {                                                               \
    f32x4 ya0 = {0.f,0.f,0.f,0.f}, ya1 = {0.f,0.f,0.f,0.f};                       \
    _Pragma("unroll") for (int kk = 0; kk < 4; ++kk) {                            \
        bf16x8 h0 = *(const bf16x8*)(smem + OFF_H + (1 - (P_)) * 32768            \
                   + (ybt * 16 + l15) * 256 + ((kk * 64 + q * 16) ^ (l15 << 4))); \
        bf16x8 h1 = *(const bf16x8*)(smem + OFF_H + (1 - (P_)) * 32768            \
                   + ((ybt + 4) * 16 + l15) * 256 + ((kk * 64 + q * 16) ^ (l15 << 4))); \
        ya0 = __builtin_amdgcn_mfma_f32_16x16x32_bf16(wor[kk], h0, ya0, 0, 0, 0); \
        ya1 = __builtin_amdgcn_mfma_f32_16x16x32_bf16(wor[kk], h1, ya1, 0, 0, 0); \
    }                                                                             \
    if (yct == 0) {                                                               \
        *(f32x4u*)ypt0 = ya0 + ybo;                                               \
        *(f32x4u*)ypt1 = ya1 + ybo;                                               \
    } else if (q == 0) {                                                          \
        ypt0[0] = ya0[0] + ybo[0];                                                \
        ypt1[0] = ya1[0] + ybo[0];                                                \
    }                                                                             \
    ypt0 += I_DIM; ypt1 += I_DIM;                                                 \
} while (0)

/* full step: ping-pong accA/accB over 8 gate tiles; 1 barrier */
#define STEP(P_, REC_) do {                                                       \
    bf16x8 hb[8];                                                                 \
    if (REC_) RB(0, P_);                                                          \
    MQ(0, 0, accA, REC_);                                                         \
    MQ(0, 1, accB, REC_);                                                         \
    if (REC_) RB(1, P_);                                                          \
    EQ(accA, 0, 0, 0, P_);                                                        \
    MQ(1, 0, accA, REC_);                                                         \
    EQ(accB, 1, 1, 0, P_);                                                        \
    MQ(1, 1, accB, REC_);                                                         \
    if (REC_) RB(2, P_);                                                          \
    EQ(accA, 2, 0, 1, P_);                                                        \
    MQ(2, 0, accA, REC_);                                                         \
    EQ(accB, 3, 1, 1, P_);                                                        \
    MQ(2, 1, accB, REC_);                                                         \
    if (REC_) YB(P_);                                                             \
    if (REC_) RB(3, P_);                                                          \
    EQ(accA, 4, 0, 2, P_);                                                        \
    MQ(3, 0, accA, REC_);                                                         \
    EQ(accB, 5, 1, 2, P_);                                                        \
    MQ(3, 1, accB, REC_);                                                         \
    EQ(accA, 6, 0, 3, P_);                                                        \
    EQ(accB, 7, 1, 3, P_);                                                        \
    xt += XSLOT;                                                                  \
    __syncthreads();                                                              \
} while (0)

__global__ __launch_bounds__(NTHR)
__attribute__((amdgpu_waves_per_eu(2, 2)))
void flowlstm(
    const float* __restrict__ x, const float* __restrict__ W_ih,
    const float* __restrict__ W_hh, const float* __restrict__ b_ih,
    const float* __restrict__ b_hh, const float* __restrict__ W_out,
    const float* __restrict__ b_out, float* __restrict__ out)
{
    __shared__ __align__(16) unsigned char smem[LDS_TOT];
    const int tid = threadIdx.x;
    const int w = tid >> 6, lane = tid & 63;
    const int l31 = lane & 31, hi = lane >> 5, l15 = lane & 15, q = lane >> 4;
    const unsigned sw15 = (unsigned)((l31 & 15) << 4);
    const int b0 = blockIdx.x * M_ROWS;

    /* ---- bulk x stage: coalesced dwords -> 32-wide frag layout + k16 plane ---- */
    {
        const float* xb = x + (size_t)b0 * XI;
        for (int j = 0; j < 81; ++j) {
            int f = tid + j * NTHR;
            if (f < NF) {
                float v = xb[f];
                unsigned uf_ = (unsigned)f;
                unsigned row = (uf_ * 51943u) >> 24;      /* f / 323 */
                unsigned s = uf_ - row * 323u;
                unsigned t = (s * 61681u) >> 20;          /* s / 17 */
                unsigned k = s - t * 17u;
                unsigned a;
                if (k == 16u)
                    a = OFF_X + t * XSLOT + 4096 + row * 2;
                else
                    a = OFF_X + t * XSLOT + (row >> 5) * 1024
                      + (((k >> 3) * 32 + (row & 31)) * 16) + (k & 7) * 2;
                *(unsigned short*)(smem + a) = f2bf(v);
            }
        }
    }
    /* ---- whh A-frags in regs, packed rows (row=l31: j=l31&7, g=l31>>3), PRE-SCALED ---- */
    bf16x8 whh[2][8];
    const int jrow = l31 & 7, grow = l31 >> 3;
    const float scl = (grow == 2) ? -K2 : -K1;
    #pragma unroll
    for (int cti = 0; cti < 2; ++cti) {
        int n = grow * H_DIM + (2 * w + cti) * 8 + jrow;
        #pragma unroll
        for (int kk = 0; kk < 8; ++kk) {
            const float* sp = W_hh + n * H_DIM + kk * 16 + hi * 8;
            FragU fu;
            #pragma unroll
            for (int e = 0; e < 8; ++e) fu.s[e] = f2bf(sp[e] * scl);
            whh[cti][kk] = fu.v;
        }
    }
    /* ---- wihr A-frags (2 per ct): k0..15 and k16(x)/k17(bias)/pad ---- */
    bf16x8 wihr[2][2];
    #pragma unroll
    for (int cti = 0; cti < 2; ++cti) {
        int n = grow * H_DIM + (2 * w + cti) * 8 + jrow;
        FragU fa, fb;
        #pragma unroll
        for (int e = 0; e < 8; ++e) {
            int k0 = hi * 8 + e;
            fa.s[e] = f2bf(W_ih[n * I_DIM + k0] * scl);   /* k0 in 0..15 < 17 */
            int k1 = 16 + hi * 8 + e;
            float v = 0.f;
            if (k1 == 16)      v = W_ih[n * I_DIM + 16] * scl;
            else if (k1 == 17) v = (b_ih[n] + b_hh[n]) * scl;
            fb.s[e] = f2bf(v);
        }
        wihr[cti][0] = fa.v;
        wihr[cti][1] = fb.v;
    }
    /* ---- wor (16x16 y path, R12-verified) ---- */
    const int ybt = w >> 1, yct = w & 1;
    const int ycol = yct * 16 + l15;
    bf16x8 wor[4];
    #pragma unroll
    for (int kk = 0; kk < 4; ++kk) {
        FragU fu;
        #pragma unroll
        for (int e = 0; e < 8; ++e)
            fu.s[e] = (ycol < I_DIM) ? f2bf(W_out[ycol * H_DIM + kk * 32 + q * 8 + e])
                                     : (unsigned short)0;
        wor[kk] = fu.v;
    }
    f32x4 ybo;
    #pragma unroll
    for (int r = 0; r < 4; ++r) {
        int col = yct * 16 + 4 * q + r;
        ybo[r] = b_out[col < I_DIM ? col : 16];
    }
    float* ypt0 = out + (size_t)(b0 + ybt * 16 + l15) * XI + (yct ? 16 : 4 * q);
    float* ypt1 = ypt0 + (size_t)64 * XI;

    float cst[32];
    #pragma unroll
    for (int i = 0; i < 32; ++i) cst[i] = 0.f;
    f32x16 accA, accB;
    unsigned xt = OFF_X;

    __syncthreads();   /* staging visible */

    /* t=0 peel: x-proj only, writes H[0] */
    STEP(0, 0);
    /* t = 1..18 */
    #pragma unroll 1
    for (int t = 1; t < T_DIM; t += 2) {
        STEP(1, 1);
        STEP(0, 1);
    }
    /* epilogue: y_18 from H[0] (pass P_=1 so YB reads H[1-1=0]) */
    YB(1);
}

extern "C" void kernel_launch(void* const* d_in, const int* in_sizes, int n_in,
                              void* d_out, int out_size, void* d_ws, size_t ws_size,
                              hipStream_t stream) {
    const float* x     = (const float*)d_in[0];
    const float* W_ih  = (const float*)d_in[1];
    const float* W_hh  = (const float*)d_in[2];
    const float* b_ih  = (const float*)d_in[3];
    const float* b_hh  = (const float*)d_in[4];
    const float* W_out = (const float*)d_in[5];
    const float* b_out = (const float*)d_in[6];
    float* out = (float*)d_out;

    dim3 grid(GRID), block(NTHR);
    flowlstm<<<grid, block, 0, stream>>>(x, W_ih, W_hh, b_ih, b_hh, W_out, b_out, out);
}

// Round 18
// 149.192 us; speedup vs baseline: 1.2508x; 1.0310x over previous
//
#include <hip/hip_runtime.h>

#define I_DIM 17
#define H_DIM 128
#define T_DIM 19
#define B_DIM 32768
#define M_ROWS 128
#define NTHR 512
#define GRID (B_DIM / M_ROWS) /* 256 = one block per CU, ONE pass */
#define XI 323
#define NF (M_ROWS * XI)      /* 41344 */
#define XSLOT 4352            /* per-t x: 4 bt x 1024B frag + 256B k16 plane */

#define OFF_H 0               /* 2 x 32768 (128 rows x 256B, full-16 swizzle) */
#define OFF_X 65536           /* 19 x 4352 = 82688 */
#define OFF_WO 148224         /* 8 frags x 1024 = 8192 */
#define LDS_TOT 156416

typedef __bf16 bf16x8 __attribute__((ext_vector_type(8)));
typedef float f32x4 __attribute__((ext_vector_type(4)));
typedef float f32x16 __attribute__((ext_vector_type(16)));
typedef float f32x4u __attribute__((ext_vector_type(4), aligned(4)));
union FragU { bf16x8 v; unsigned short s[8]; uint4 u; };

#define K1 1.4426950408889634f
#define K2 2.8853900817779268f

__device__ __forceinline__ unsigned short f2bf(float f) {
    union { float f; unsigned u; } x; x.f = f;
    return (unsigned short)((x.u + 0x8000u) >> 16);
}

/* read 4 recurrent B-frags (h K-chunks HALF_*4..+3) for batch-tile BT_ from H[1-P] */
#define RB4(BT_, HALF_, P_) do {                                                  \
    _Pragma("unroll") for (int kk = 0; kk < 4; ++kk)                              \
        hb[kk] = *(const bf16x8*)(smem + OFF_H + (1 - (P_)) * 32768               \
                 + ((BT_) * 32 + l31) * 256                                       \
                 + (((((HALF_) * 4 + kk) * 32) + hi * 16) ^ sw15));               \
} while (0)

/* x-projection init for one 32x32 gate tile (2 MFMAs, bias folded at k17) */
#define MQX(BT_, CTI_, ACC_) do {                                                 \
    FragU f1; f1.v = *(const bf16x8*)(smem + xt + (BT_) * 1024 + lane * 16);      \
    FragU f2; f2.u = (uint4){0u, 0u, 0u, 0u};                                     \
    if (hi == 0) {                                                                \
        f2.s[0] = *(const unsigned short*)(smem + xt + 4096 + ((BT_) * 32 + l31) * 2); \
        f2.s[1] = (unsigned short)0x3F80;                                         \
    }                                                                             \
    f32x16 z = {0.f,0.f,0.f,0.f,0.f,0.f,0.f,0.f,0.f,0.f,0.f,0.f,0.f,0.f,0.f,0.f};\
    ACC_ = __builtin_amdgcn_mfma_f32_32x32x16_bf16(wihr[CTI_][0], f1.v, z, 0, 0, 0); \
    ACC_ = __builtin_amdgcn_mfma_f32_32x32x16_bf16(wihr[CTI_][1], f2.v, ACC_, 0, 0, 0); \
} while (0)

/* 4 recurrent MFMAs into ACC_ using hb[0..3] = K-chunks KLO_..KLO_+3 */
#define MQH(ACC_, CTI_, KLO_) do {                                                \
    _Pragma("unroll") for (int kk = 0; kk < 4; ++kk)                              \
        ACC_ = __builtin_amdgcn_mfma_f32_32x32x16_bf16(whh[CTI_][(KLO_) + kk], hb[kk], ACC_, 0, 0, 0); \
} while (0)

/* elementwise for one tile: 4 i/f/g/o quadruples/lane; b64 h-write into H[P] */
#define EQ(ACC_, TI_, CTI_, BT_, P_) do {                                         \
    unsigned long long hp = 0ull;                                                 \
    _Pragma("unroll") for (int jj = 0; jj < 4; ++jj) {                            \
        float ui = __builtin_amdgcn_exp2f(ACC_[jj]);                              \
        float uf = __builtin_amdgcn_exp2f(ACC_[4 + jj]);                          \
        float vg = __builtin_amdgcn_exp2f(ACC_[8 + jj]);                          \
        float uo = __builtin_amdgcn_exp2f(ACC_[12 + jj]);                         \
        float A_ = 1.f + ui, F_ = 1.f + uf, G_ = 1.f + vg;                        \
        float AG = A_ * G_;                                                       \
        int ci = (TI_) * 4 + jj;                                                  \
        float c = (cst[ci] * AG + (1.f - vg) * F_) * __builtin_amdgcn_rcpf(F_ * AG); \
        cst[ci] = c;                                                              \
        float vc = __builtin_amdgcn_exp2f(-K2 * c);                               \
        float h = (1.f - vc) * __builtin_amdgcn_rcpf((1.f + uo) * (1.f + vc));    \
        union { float f; unsigned u; } hu; hu.f = h;                              \
        hp |= (unsigned long long)((hu.u + 0x8000u) >> 16) << (16 * jj);          \
    }                                                                             \
    *(unsigned long long*)(smem + OFF_H + (P_) * 32768 + ((BT_) * 32 + l31) * 256 \
        + (((2 * w + (CTI_)) * 16 + hi * 8) ^ sw15)) = hp;                        \
} while (0)

/* y_{t-1} via 16x16 (R12-verified); reads H[1-P]; wor from LDS */
#define YB(P_) do {                                                               \
    f32x4 ya0 = {0.f,0.f,0.f,0.f}, ya1 = {0.f,0.f,0.f,0.f};                       \
    _Pragma("unroll") for (int kk = 0; kk < 4; ++kk) {                            \
        bf16x8 wa = *(const bf16x8*)(smem + vwo + kk * 1024);                     \
        bf16x8 h0 = *(const bf16x8*)(smem + OFF_H + (1 - (P_)) * 32768            \
                   + (ybt * 16 + l15) * 256 + ((kk * 64 + q * 16) ^ (l15 << 4))); \
        bf16x8 h1 = *(const bf16x8*)(smem + OFF_H + (1 - (P_)) * 32768            \
                   + ((ybt + 4) * 16 + l15) * 256 + ((kk * 64 + q * 16) ^ (l15 << 4))); \
        ya0 = __builtin_amdgcn_mfma_f32_16x16x32_bf16(wa, h0, ya0, 0, 0, 0);      \
        ya1 = __builtin_amdgcn_mfma_f32_16x16x32_bf16(wa, h1, ya1, 0, 0, 0);      \
    }                                                                             \
    if (yct == 0) {                                                               \
        *(f32x4u*)ypt0 = ya0 + ybo;                                               \
        *(f32x4u*)ypt1 = ya1 + ybo;                                               \
    } else if (q == 0) {                                                          \
        ypt0[0] = ya0[0] + ybo[0];                                                \
        ypt1[0] = ya1[0] + ybo[0];                                                \
    }                                                                             \
    ypt0 += I_DIM; ypt1 += I_DIM;                                                 \
} while (0)

/* full step: ping-pong accA/accB over 8 gate tiles; hb[4] reused; 1 barrier */
#define STEP(P_, REC_) do {                                                       \
    bf16x8 hb[4];                                                                 \
    MQX(0, 0, accA); MQX(0, 1, accB);                                             \
    if (REC_) {                                                                   \
        RB4(0, 0, P_); MQH(accA, 0, 0); MQH(accB, 1, 0);                          \
        RB4(0, 1, P_); MQH(accA, 0, 4); MQH(accB, 1, 4);                          \
    }                                                                             \
    EQ(accA, 0, 0, 0, P_); MQX(1, 0, accA);                                       \
    EQ(accB, 1, 1, 0, P_); MQX(1, 1, accB);                                       \
    if (REC_) {                                                                   \
        RB4(1, 0, P_); MQH(accA, 0, 0); MQH(accB, 1, 0);                          \
        RB4(1, 1, P_); MQH(accA, 0, 4); MQH(accB, 1, 4);                          \
    }                                                                             \
    if (REC_) YB(P_);                                                             \
    EQ(accA, 2, 0, 1, P_); MQX(2, 0, accA);                                       \
    EQ(accB, 3, 1, 1, P_); MQX(2, 1, accB);                                       \
    if (REC_) {                                                                   \
        RB4(2, 0, P_); MQH(accA, 0, 0); MQH(accB, 1, 0);                          \
        RB4(2, 1, P_); MQH(accA, 0, 4); MQH(accB, 1, 4);                          \
    }                                                                             \
    EQ(accA, 4, 0, 2, P_); MQX(3, 0, accA);                                       \
    EQ(accB, 5, 1, 2, P_); MQX(3, 1, accB);                                       \
    if (REC_) {                                                                   \
        RB4(3, 0, P_); MQH(accA, 0, 0); MQH(accB, 1, 0);                          \
        RB4(3, 1, P_); MQH(accA, 0, 4); MQH(accB, 1, 4);                          \
    }                                                                             \
    EQ(accA, 6, 0, 3, P_);                                                        \
    EQ(accB, 7, 1, 3, P_);                                                        \
    xt += XSLOT;                                                                  \
    __syncthreads();                                                              \
} while (0)

__global__ __launch_bounds__(NTHR)
__attribute__((amdgpu_waves_per_eu(2, 2)))
void flowlstm(
    const float* __restrict__ x, const float* __restrict__ W_ih,
    const float* __restrict__ W_hh, const float* __restrict__ b_ih,
    const float* __restrict__ b_hh, const float* __restrict__ W_out,
    const float* __restrict__ b_out, float* __restrict__ out)
{
    __shared__ __align__(16) unsigned char smem[LDS_TOT];
    const int tid = threadIdx.x;
    const int w = tid >> 6, lane = tid & 63;
    const int l31 = lane & 31, hi = lane >> 5, l15 = lane & 15, q = lane >> 4;
    const unsigned sw15 = (unsigned)((l31 & 15) << 4);
    const int b0 = blockIdx.x * M_ROWS;

    /* ---- bulk x stage: coalesced dwords -> 32-wide frag layout + k16 plane ---- */
    {
        const float* xb = x + (size_t)b0 * XI;
        for (int j = 0; j < 81; ++j) {
            int f = tid + j * NTHR;
            if (f < NF) {
                float v = xb[f];
                unsigned uf_ = (unsigned)f;
                unsigned row = (uf_ * 51943u) >> 24;      /* f / 323 */
                unsigned s = uf_ - row * 323u;
                unsigned t = (s * 61681u) >> 20;          /* s / 17 */
                unsigned k = s - t * 17u;
                unsigned a;
                if (k == 16u)
                    a = OFF_X + t * XSLOT + 4096 + row * 2;
                else
                    a = OFF_X + t * XSLOT + (row >> 5) * 1024
                      + (((k >> 3) * 32 + (row & 31)) * 16) + (k & 7) * 2;
                *(unsigned short*)(smem + a) = f2bf(v);
            }
        }
    }
    /* ---- W_out fragments -> LDS (8 frags: ct*4+kk, N pad 17->32) ---- */
    {
        int ln = tid & 63, f = tid >> 6;
        int kk = f & 3, ct = f >> 2;
        int o = ct * 16 + (ln & 15);
        int kb = kk * 32 + (ln >> 4) * 8;
        FragU fu;
        #pragma unroll
        for (int e = 0; e < 8; ++e)
            fu.s[e] = (o < I_DIM) ? f2bf(W_out[o * H_DIM + kb + e]) : (unsigned short)0;
        *(uint4*)(smem + OFF_WO + f * 1024 + ln * 16) = fu.u;
    }
    /* ---- whh A-frags in regs, packed rows (j=l31&7, g=l31>>3), PRE-SCALED ---- */
    bf16x8 whh[2][8];
    const int jrow = l31 & 7, grow = l31 >> 3;
    const float scl = (grow == 2) ? -K2 : -K1;
    #pragma unroll
    for (int cti = 0; cti < 2; ++cti) {
        int n = grow * H_DIM + (2 * w + cti) * 8 + jrow;
        #pragma unroll
        for (int kk = 0; kk < 8; ++kk) {
            const float* sp = W_hh + n * H_DIM + kk * 16 + hi * 8;
            FragU fu;
            #pragma unroll
            for (int e = 0; e < 8; ++e) fu.s[e] = f2bf(sp[e] * scl);
            whh[cti][kk] = fu.v;
        }
    }
    /* ---- wihr A-frags (2 per ct): k0..15 and k16(x)/k17(bias)/pad ---- */
    bf16x8 wihr[2][2];
    #pragma unroll
    for (int cti = 0; cti < 2; ++cti) {
        int n = grow * H_DIM + (2 * w + cti) * 8 + jrow;
        FragU fa, fb;
        #pragma unroll
        for (int e = 0; e < 8; ++e) {
            int k0 = hi * 8 + e;
            fa.s[e] = f2bf(W_ih[n * I_DIM + k0] * scl);
            int k1 = 16 + hi * 8 + e;
            float v = 0.f;
            if (k1 == 16)      v = W_ih[n * I_DIM + 16] * scl;
            else if (k1 == 17) v = (b_ih[n] + b_hh[n]) * scl;
            fb.s[e] = f2bf(v);
        }
        wihr[cti][0] = fa.v;
        wihr[cti][1] = fb.v;
    }
    /* ---- y constants (wor lives in LDS) ---- */
    const int ybt = w >> 1, yct = w & 1;
    const unsigned vwo = (unsigned)(OFF_WO + yct * 4096 + lane * 16);
    f32x4 ybo;
    #pragma unroll
    for (int r = 0; r < 4; ++r) {
        int col = yct * 16 + 4 * q + r;
        ybo[r] = b_out[col < I_DIM ? col : 16];
    }
    float* ypt0 = out + (size_t)(b0 + ybt * 16 + l15) * XI + (yct ? 16 : 4 * q);
    float* ypt1 = ypt0 + (size_t)64 * XI;

    float cst[32];
    #pragma unroll
    for (int i = 0; i < 32; ++i) cst[i] = 0.f;
    f32x16 accA, accB;
    unsigned xt = OFF_X;

    __syncthreads();   /* staging visible */

    /* t=0 peel: x-proj only, writes H[0] */
    STEP(0, 0);
    /* t = 1..18 */
    #pragma unroll 1
    for (int t = 1; t < T_DIM; t += 2) {
        STEP(1, 1);
        STEP(0, 1);
    }
    /* epilogue: y_18 from H[0] (P_=1 so YB reads H[0]) */
    YB(1);
}

extern "C" void kernel_launch(void* const* d_in, const int* in_sizes, int n_in,
                              void* d_out, int out_size, void* d_ws, size_t ws_size,
                              hipStream_t stream) {
    const float* x     = (const float*)d_in[0];
    const float* W_ih  = (const float*)d_in[1];
    const float* W_hh  = (const float*)d_in[2];
    const float* b_ih  = (const float*)d_in[3];
    const float* b_hh  = (const float*)d_in[4];
    const float* W_out = (const float*)d_in[5];
    const float* b_out = (const float*)d_in[6];
    float* out = (float*)d_out;

    dim3 grid(GRID), block(NTHR);
    flowlstm<<<grid, block, 0, stream>>>(x, W_ih, W_hh, b_ih, b_hh, W_out, b_out, out);
}